// Round 10
// baseline (300.297 us; speedup 1.0000x reference)
//
#include <hip/hip_runtime.h>
#include <hip/hip_bf16.h>

typedef unsigned short u16;
typedef __attribute__((ext_vector_type(8))) short short8;   // 8 bf16 (4 VGPRs)
typedef __attribute__((ext_vector_type(4))) float f32x4;

#define NN 9
#define DX 128
#define KP 64
#define LL 32
#define NALL 100000
#define NBM 4

#define MFMA(a, b, c) __builtin_amdgcn_mfma_f32_16x16x32_bf16(a, b, c, 0, 0, 0)

// ---------- cross-kernel tables (written by k_proto, read by k_main) ----------
__device__ __align__(16) float g_tns[LL * NN];        // normalized theta_s [l][j]
__device__ __align__(16) float g_hprn[KP];            // ||h_proto_root||^2 [k]
__device__ __align__(16) float g_hpt[32 * KP];        // hp^T [j][k]
__device__ __align__(16) float g_rpst[NN * KP];       // sorted proto_rad [m][k]
// MFMA fragment-packed B tables (bf16)
__device__ __align__(16) u16   g_pBw[16384];          // x_lin_w: K=128, N=128
__device__ __align__(16) u16   g_pBt[4096];           // tnx:  K=128, N=32
__device__ __align__(16) u16   g_pBr[8192];           // hprt: K=128, N=64
__device__ __align__(16) u16   g_pBx[36864];          // sw feat [pf^2|pf]: K=576, N=64
__device__ __align__(16) u16   g_pBs[36864];          // sw str  [qf^2|qf]: K=576, N=64

__device__ __forceinline__ float bf2f(u16 u) {
    union { unsigned u; float f; } v; v.u = ((unsigned)u) << 16; return v.f;
}
__device__ __forceinline__ u16 f2bf(float f) {
    __hip_bfloat16 h = __float2bfloat16(f);
    union { __hip_bfloat16 h; u16 u; } v; v.h = h; return v.u;
}
__device__ __forceinline__ float ldv(const void* p, long i, int f32) {
    return f32 ? ((const float*)p)[i] : bf2f(((const u16*)p)[i]);
}
__device__ __forceinline__ float sigmoidf(float x) { return 1.f / (1.f + expf(-x)); }

__device__ __forceinline__ int bfrag_idx(int ksteps, int ncol, int kd) {
    int ntile = ncol >> 4, n = ncol & 15;
    int kstep = kd >> 5, quad = (kd >> 3) & 3, j = kd & 7;
    return ((ntile * ksteps + kstep) * 64 + quad * 16 + n) * 8 + j;
}

__device__ __forceinline__ void rank9(const float* v, int* r) {
#pragma unroll
    for (int m = 0; m < 9; m++) {
        int rk = 0;
#pragma unroll
        for (int n = 0; n < 9; n++)
            rk += (v[n] < v[m]) || (v[n] == v[m] && n < m);
        r[m] = rk;
    }
}

// ---------------- kernel B: per-k prototype chain; blk0 publishes packed tables ----------------
struct PSMem {
    u16   Wf[16384];        // W B-frags (local)
    u16   pBtL[4096];       // theta_x B-frags (local)
    float tnsL[LL * NN];
    float hX[1280];         // proto h rows f32
    float pbX[288], pbS[288];
    float hst[81], hsn[81];
};
__global__ __launch_bounds__(256) void k_proto(
    const void* xlw, const void* xlb, const void* xlg, const void* xlbt,
    const void* slg, const void* slb, const void* wn_w1,
    const void* proto_root, const void* proto_neigh,
    const void* proto_rad, const void* proto_dn,
    const void* theta_x, const void* theta_s) {
    __shared__ __align__(16) PSMem S;
    int k = blockIdx.x, t = threadIdx.x, lane = t & 63, w = t >> 6;
    const int f32 = (((const u16*)xlg)[0] == 0);
    int fm = lane & 15, quad = lane >> 4;

    // ---- A: pack W + theta tables into LDS ----
    for (int i = t; i < 16384; i += 256) {
        int c = i >> 7, d = i & 127;
        S.Wf[bfrag_idx(4, d, c)] = f2bf(ldv(xlw, i, f32));
    }
    if (t < 32) {
        float s = 0;
        for (int d = 0; d < 128; d++) { float v = ldv(theta_x, t * 128 + d, f32); s = fmaf(v, v, s); }
        float inv = 1.f / sqrtf(s);
        for (int d = 0; d < 128; d++)
            S.pBtL[bfrag_idx(4, t, d)] = f2bf(ldv(theta_x, t * 128 + d, f32) * inv);
    } else if (t < 64) {
        int l = t - 32;
        float s = 0;
        for (int j = 0; j < 9; j++) { float v = ldv(theta_s, l * 9 + j, f32); s = fmaf(v, v, s); }
        float inv = 1.f / sqrtf(s);
        for (int j = 0; j < 9; j++) S.tnsL[l * 9 + j] = ldv(theta_s, l * 9 + j, f32) * inv;
    }
    __syncthreads();

    // ---- B: wave0 = proto lin+LN via MFMA; w3 = C build; t==128 = rpst ----
    if (w == 0) {
        float bias[8], gg[8], bb[8];
#pragma unroll
        for (int nt = 0; nt < 8; nt++) {
            int col = nt * 16 + fm;
            bias[nt] = ldv(xlb, col, f32);
            gg[nt]   = ldv(xlg, col, f32);
            bb[nt]   = ldv(xlbt, col, f32);
        }
        f32x4 acc[8];
#pragma unroll
        for (int nt = 0; nt < 8; nt++) acc[nt] = (f32x4){0.f, 0.f, 0.f, 0.f};
#pragma unroll
        for (int ks = 0; ks < 4; ks++) {
            short8 af = {0, 0, 0, 0, 0, 0, 0, 0};
            if (fm < 10) {
                const void* ab = (fm < 9) ? proto_neigh : proto_root;
                long ao = (fm < 9) ? (long)(k * 9 + fm) * 128 : (long)k * 128;
                u16* ap = (u16*)&af;
#pragma unroll
                for (int j = 0; j < 8; j++)
                    ap[j] = f2bf(ldv(ab, ao + ks * 32 + quad * 8 + j, f32));
            }
#pragma unroll
            for (int nt = 0; nt < 8; nt++) {
                short8 bf = *(const short8*)(S.Wf + ((nt * 4 + ks) * 64 + lane) * 8);
                acc[nt] = MFMA(af, bf, acc[nt]);
            }
        }
#pragma unroll
        for (int nt = 0; nt < 8; nt++)
#pragma unroll
            for (int reg = 0; reg < 4; reg++) acc[nt][reg] += bias[nt];
#pragma unroll
        for (int reg = 0; reg < 4; reg++) {
            float s = 0, q = 0;
#pragma unroll
            for (int nt = 0; nt < 8; nt++) {
                s += acc[nt][reg];
                q = fmaf(acc[nt][reg], acc[nt][reg], q);
            }
#pragma unroll
            for (int m = 1; m < 16; m <<= 1) { s += __shfl_xor(s, m); q += __shfl_xor(q, m); }
            float mu = s * (1.f / 128.f);
            float var = fmaxf(q * (1.f / 128.f) - mu * mu, 0.f);
            float rs = rsqrtf(var + 1e-5f);
            int rowD = quad * 4 + reg;
            if (rowD < 10) {
#pragma unroll
                for (int nt = 0; nt < 8; nt++)
                    S.hX[rowD * 128 + nt * 16 + fm] = (acc[nt][reg] - mu) * rs * gg[nt] + bb[nt];
            }
        }
    }
    if (w == 3) {   // C build
        for (int i = lane; i < 81; i += 64) {
            int ii = i / 9, jj = i % 9; float v = 0.f;
            if (ii != jj) {
                int a = (ii < jj) ? ii : jj, b2 = (ii < jj) ? jj : ii;
                int p = a * 8 - a * (a - 1) / 2 + (b2 - a - 1);
                v = sigmoidf(ldv(proto_dn, p * 64 + k, f32));
            }
            S.hst[i] = v;
        }
    }
    if (t == 128) {
        float v[9]; int r[9];
#pragma unroll
        for (int m = 0; m < 9; m++) v[m] = ldv(proto_rad, k * 9 + m, f32);
        rank9(v, r);
#pragma unroll
        for (int m = 0; m < 9; m++) g_rpst[r[m] * 64 + k] = v[m];
    }
    __syncthreads();

    // ---- C: publish (blk0), pBr, hprn, hpt, proj MFMA ----
    if (k == 0) {
        for (int i = t; i < 16384; i += 256) g_pBw[i] = S.Wf[i];
        for (int i = t; i < 4096; i += 256) g_pBt[i] = S.pBtL[i];
        for (int i = t; i < 288; i += 256) g_tns[i] = S.tnsL[i];
    }
    if (t < 128) g_pBr[bfrag_idx(4, k, t)] = f2bf(S.hX[9 * 128 + t]);
    if (w == 0) {
        float v0 = S.hX[9 * 128 + lane], v1 = S.hX[9 * 128 + 64 + lane];
        float q = v0 * v0 + v1 * v1;
#pragma unroll
        for (int m = 32; m >= 1; m >>= 1) q += __shfl_xor(q, m);
        if (lane == 0) g_hprn[k] = q;
    }
    if (t >= 128 && t < 160) {
        int j = t - 128;
        float acc = 0;
        for (int d = 0; d < 128; d++)
            acc = fmaf(S.hX[9 * 128 + d], ldv(wn_w1, (128 + d) * 32 + j, f32), acc);
        g_hpt[j * 64 + k] = acc;
    }
    if (w == 1) {   // feature proj MFMA
        f32x4 acc0 = {0.f, 0.f, 0.f, 0.f}, acc1 = {0.f, 0.f, 0.f, 0.f};
#pragma unroll
        for (int ks = 0; ks < 4; ks++) {
            short8 af = {0, 0, 0, 0, 0, 0, 0, 0};
            if (fm < 9) {
                u16* ap = (u16*)&af;
#pragma unroll
                for (int j = 0; j < 8; j++) ap[j] = f2bf(S.hX[fm * 128 + ks * 32 + quad * 8 + j]);
            }
            short8 b0 = *(const short8*)(S.pBtL + ((0 * 4 + ks) * 64 + lane) * 8);
            short8 b1 = *(const short8*)(S.pBtL + ((1 * 4 + ks) * 64 + lane) * 8);
            acc0 = MFMA(af, b0, acc0);
            acc1 = MFMA(af, b1, acc1);
        }
#pragma unroll
        for (int reg = 0; reg < 4; reg++) {
            int row = quad * 4 + reg;
            if (row < 9) {
                S.pbX[row * 32 + fm]      = acc0[reg];
                S.pbX[row * 32 + 16 + fm] = acc1[reg];
            }
        }
    }
    __syncthreads();

    // ---- D: col sort C; pbX sort -> g_pBx ----
    if (t < 9) {
        float v[9]; int r[9];
#pragma unroll
        for (int i = 0; i < 9; i++) v[i] = S.hst[i * 9 + t];
        rank9(v, r);
#pragma unroll
        for (int i = 0; i < 9; i++) S.hst[r[i] * 9 + t] = v[i];
    }
    if (t >= 32 && t < 64) {
        int l = t - 32;
        float v[9]; int r[9];
#pragma unroll
        for (int m = 0; m < 9; m++) v[m] = S.pbX[m * 32 + l];
        rank9(v, r);
#pragma unroll
        for (int m = 0; m < 9; m++) {
            int kd = l * 9 + r[m];
            g_pBx[bfrag_idx(18, k, kd)]       = f2bf(v[m] * v[m]);
            g_pBx[bfrag_idx(18, k, 288 + kd)] = f2bf(v[m]);
        }
    }
    __syncthreads();
    if (t < 9) {    // LN rows
        float mu = 0;
#pragma unroll
        for (int j = 0; j < 9; j++) mu += S.hst[t * 9 + j];
        mu *= (1.f / 9.f);
        float var = 0;
#pragma unroll
        for (int j = 0; j < 9; j++) { float d0 = S.hst[t * 9 + j] - mu; var = fmaf(d0, d0, var); }
        var *= (1.f / 9.f);
        float rs = rsqrtf(var + 1e-5f);
#pragma unroll
        for (int j = 0; j < 9; j++)
            S.hsn[t * 9 + j] = (S.hst[t * 9 + j] - mu) * rs * ldv(slg, j, f32) + ldv(slb, j, f32);
    }
    __syncthreads();
    if (t < 64) {   // structural projections
        int l = t & 31;
        int m0 = (t < 32) ? 0 : 5, m1 = (t < 32) ? 5 : 9;
        for (int m = m0; m < m1; m++) {
            float a = 0;
#pragma unroll
            for (int j = 0; j < 9; j++) a = fmaf(S.hsn[m * 9 + j], S.tnsL[l * 9 + j], a);
            S.pbS[m * 32 + l] = a;
        }
    }
    __syncthreads();
    if (t < 32) {   // sort pbS -> g_pBs
        float v[9]; int r[9];
#pragma unroll
        for (int m = 0; m < 9; m++) v[m] = S.pbS[m * 32 + t];
        rank9(v, r);
#pragma unroll
        for (int m = 0; m < 9; m++) {
            int kd = t * 9 + r[m];
            g_pBs[bfrag_idx(18, k, kd)]       = f2bf(v[m] * v[m]);
            g_pBs[bfrag_idx(18, k, 288 + kd)] = f2bf(v[m]);
        }
    }
}

// ---------------- main kernel: 4 b's per block, one wave per b; lin fused ----------------
struct M3 {
    u16   h[NBM][1280];     // own b's LN'd h rows, bf16
    u16   Cf[NBM][576];
    u16   Cs[NBM][576];
    float pb[NBM][288];
    float df[NBM][100];
    float hst[NBM][81], hsn[NBM][81];
    float drad[NBM][64];
    float hbv[NBM][32];
    float hpool[NBM][128];
    float rbss[NBM][9], wrad[NBM][9];
    float sc[NBM][8];       // 1:hrn 2:alpha 3:t1x 4:t1s
};
__global__ __launch_bounds__(256) void k_main(
    const void* adj, const int* idxs, const void* feat,
    const void* xlb, const void* xlg, const void* xlbt,
    const void* slg, const void* slb,
    const void* an_w1, const void* an_b1, const void* an_w2, const void* an_b2,
    const void* wn_w1, const void* wn_b1, const void* wn_w2, const void* wn_b2,
    const void* alpha_raw, const void* w_raw, const void* log_gamma,
    void* out, int B) {
    __shared__ __align__(16) M3 S;
    int t = threadIdx.x, lane = t & 63, w = t >> 6;
    const int f32 = (((const u16*)xlg)[0] == 0);
    int fm = lane & 15, quad = lane >> 4;
    int bw = blockIdx.x * NBM + w;
    bool bv = (bw < B);

    unsigned long long mb = 0; float nv = 1e-9f, inv = 0.f;

    // ================= P_lin: own b's lin+LN via MFMA =================
    if (bv) {
        int idr = NALL;
        if (fm < 10) idr = idxs[bw * 10 + fm];
        float bias[8], gg[8], bb[8];
#pragma unroll
        for (int nt = 0; nt < 8; nt++) {
            int col = nt * 16 + fm;
            bias[nt] = ldv(xlb, col, f32);
            gg[nt]   = ldv(xlg, col, f32);
            bb[nt]   = ldv(xlbt, col, f32);
        }
        f32x4 acc[8];
#pragma unroll
        for (int nt = 0; nt < 8; nt++) acc[nt] = (f32x4){0.f, 0.f, 0.f, 0.f};
#pragma unroll
        for (int ks = 0; ks < 4; ks++) {
            short8 af = {0, 0, 0, 0, 0, 0, 0, 0};
            if (idr != NALL) {
                if (f32) {
                    const f32x4* src = (const f32x4*)((const float*)feat + (long)idr * 128 + ks * 32 + quad * 8);
                    f32x4 v0 = src[0], v1 = src[1];
                    u16* ap = (u16*)&af;
#pragma unroll
                    for (int j = 0; j < 4; j++) { ap[j] = f2bf(v0[j]); ap[4 + j] = f2bf(v1[j]); }
                } else {
                    af = *(const short8*)((const u16*)feat + (long)idr * 128 + ks * 32 + quad * 8);
                }
            }
#pragma unroll
            for (int nt = 0; nt < 8; nt++) {
                short8 bf = *(const short8*)(g_pBw + ((nt * 4 + ks) * 64 + lane) * 8);
                acc[nt] = MFMA(af, bf, acc[nt]);
            }
        }
#pragma unroll
        for (int nt = 0; nt < 8; nt++)
#pragma unroll
            for (int reg = 0; reg < 4; reg++) acc[nt][reg] += bias[nt];
#pragma unroll
        for (int reg = 0; reg < 4; reg++) {
            float s = 0, q = 0;
#pragma unroll
            for (int nt = 0; nt < 8; nt++) {
                s += acc[nt][reg];
                q = fmaf(acc[nt][reg], acc[nt][reg], q);
            }
#pragma unroll
            for (int m = 1; m < 16; m <<= 1) { s += __shfl_xor(s, m); q += __shfl_xor(q, m); }
            float mu = s * (1.f / 128.f);
            float var = fmaxf(q * (1.f / 128.f) - mu * mu, 0.f);
            float rs = rsqrtf(var + 1e-5f);
            int rowD = quad * 4 + reg;
            if (rowD < 10) {
#pragma unroll
                for (int nt = 0; nt < 8; nt++)
                    S.h[w][rowD * 128 + nt * 16 + fm] = f2bf((acc[nt][reg] - mu) * rs * gg[nt] + bb[nt]);
            }
        }
    }

    // ================= P0 (per wave, own b; reads own-wave LDS h) =================
    if (bv) {
        bool valid = false;
        if (lane < 10) {
            int id = idxs[bw * 10 + lane];
            valid = (lane == 0) || (id != NALL);
        }
        mb = __ballot(valid);
        nv = (float)__popcll(mb & 0x3FEull) + 1e-9f;
        inv = 1.f / nv;
        unsigned rowbits = 0;
        if (lane < 10) {
            for (int j = 0; j < 10; j++)
                if (ldv(adj, (long)bw * 100 + lane * 10 + j, f32) > 1e-5f) rowbits |= 1u << j;
        }
        int dl[10];
#pragma unroll
        for (int j = 0; j < 10; j++) dl[j] = (j == lane) ? 0 : (((rowbits >> j) & 1) ? 1 : 10);
        unsigned reach = (lane < 10) ? (rowbits | (1u << lane)) : 0u;
        for (int s = 2; s <= 9; s++) {
            unsigned nr = reach;
#pragma unroll
            for (int j = 0; j < 10; j++) {
                unsigned rj = __shfl(rowbits, j);
                if ((reach >> j) & 1) nr |= rj;
            }
            unsigned add = nr & ~reach;
#pragma unroll
            for (int j = 0; j < 10; j++) if ((add >> j) & 1) dl[j] = s;
            reach = nr;
            if (__all(add == 0)) break;
        }
        if (lane < 10) {
            int mi = (int)((mb >> lane) & 1);
#pragma unroll
            for (int j = 0; j < 10; j++) {
                int mj = (int)((mb >> j) & 1);
                S.df[w][lane * 10 + j] = (mi && mj) ? (float)dl[j] * 0.1f : 1.0f;
            }
            if (lane == 0) {
                float v[9]; int r[9];
#pragma unroll
                for (int m = 0; m < 9; m++)
                    v[m] = ((mb >> (1 + m)) & 1) ? (float)dl[1 + m] * 0.1f : 1.0f;
                rank9(v, r);
#pragma unroll
                for (int m = 0; m < 9; m++) {
                    S.rbss[w][r[m]] = v[m];
                    S.wrad[w][r[m]] = (((mb >> (1 + m)) & 1) ? 1.f : 0.f) * inv;
                }
            }
        }
        {   // ||h_root||^2 (row 0 of own h)
            float v0 = bf2f(S.h[w][lane]), v1 = bf2f(S.h[w][64 + lane]);
            float q = v0 * v0 + v1 * v1;
#pragma unroll
            for (int m = 32; m >= 1; m >>= 1) q += __shfl_xor(q, m);
            if (lane == 0) S.sc[w][1] = q;
        }
        for (int dd = lane; dd < 128; dd += 64) {
            float a = 0;
#pragma unroll
            for (int m = 0; m < 9; m++) {
                float hv = bf2f(S.h[w][(1 + m) * 128 + dd]);
                float msk = ((mb >> (1 + m)) & 1) ? 1.f : 0.f;
                a = fmaf(hv, msk, a);
            }
            S.hpool[w][dd] = a * inv;
        }
        {   // feature projections MFMA (A from own LDS h)
            f32x4 acc0 = {0.f, 0.f, 0.f, 0.f}, acc1 = {0.f, 0.f, 0.f, 0.f};
            const u16* arow = S.h[w] + (1 + fm) * 128;
#pragma unroll
            for (int ks = 0; ks < 4; ks++) {
                short8 af = {0, 0, 0, 0, 0, 0, 0, 0};
                if (fm < 9) af = *(const short8*)(arow + ks * 32 + quad * 8);
                short8 b0 = *(const short8*)(g_pBt + ((0 * 4 + ks) * 64 + lane) * 8);
                short8 b1 = *(const short8*)(g_pBt + ((1 * 4 + ks) * 64 + lane) * 8);
                acc0 = MFMA(af, b0, acc0);
                acc1 = MFMA(af, b1, acc1);
            }
#pragma unroll
            for (int reg = 0; reg < 4; reg++) {
                int row = quad * 4 + reg;
                if (row < 9) {
                    S.pb[w][row * 32 + fm]      = acc0[reg];
                    S.pb[w][row * 32 + 16 + fm] = acc1[reg];
                }
            }
        }
    }
    __syncthreads();   // SY1

    // ================= P1 =================
    if (bv) {
        float t1 = 0;
        if (lane < 32) {
            float v[9]; int r[9];
#pragma unroll
            for (int m = 0; m < 9; m++) v[m] = S.pb[w][m * 32 + lane];
            rank9(v, r);
#pragma unroll
            for (int m = 0; m < 9; m++) {
                float wgt = (((mb >> (1 + m)) & 1) ? 1.f : 0.f) * inv;
                int slot = lane * 9 + r[m];
                S.Cf[w][slot]       = f2bf(wgt);
                S.Cf[w][288 + slot] = f2bf(-2.f * wgt * v[m]);
                t1 = fmaf(wgt * v[m], v[m], t1);
            }
        }
#pragma unroll
        for (int m = 16; m >= 1; m >>= 1) t1 += __shfl_xor(t1, m);
        if (lane == 0) S.sc[w][3] = t1;
        if (lane < 9) {
            float v[9]; int r[9];
#pragma unroll
            for (int i = 0; i < 9; i++) v[i] = S.df[w][(1 + i) * 10 + 1 + lane];
            rank9(v, r);
#pragma unroll
            for (int i = 0; i < 9; i++) S.hst[w][r[i] * 9 + lane] = v[i];
        }
        {
            float acc = 0;
#pragma unroll
            for (int m = 0; m < 9; m++) {
                float d0 = S.rbss[w][m] - g_rpst[m * 64 + lane];
                acc = fmaf(d0 * d0, S.wrad[w][m], acc);
            }
            S.drad[w][lane] = acc;
        }
        {
            int j = lane & 31, half = lane >> 5;
            float acc = 0;
            for (int d = half * 64; d < half * 64 + 64; d++)
                acc = fmaf(S.hpool[w][d], ldv(an_w1, d * 32 + j, f32), acc);
            acc += __shfl_xor(acc, 32);
            float red = 0;
            if (lane < 32)
                red = fmaxf(acc + ldv(an_b1, j, f32), 0.f) * ldv(an_w2, j, f32);
#pragma unroll
            for (int m = 16; m >= 1; m >>= 1) red += __shfl_xor(red, m);
            if (lane == 0)
                S.sc[w][2] = sigmoidf(ldv(alpha_raw, 0, f32) + red + ldv(an_b2, 0, f32));
        }
        {
            int j = lane & 31, half = lane >> 5;
            float acc = 0;
            for (int d = half * 64; d < half * 64 + 64; d++)
                acc = fmaf(bf2f(S.h[w][d]), ldv(wn_w1, d * 32 + j, f32), acc);
            acc += __shfl_xor(acc, 32);
            if (lane < 32) S.hbv[w][j] = acc + ldv(wn_b1, j, f32);
        }
    }
    __syncthreads();   // SY2

    // ================= P2: LN of sorted structural rows =================
    if (bv && lane < 9) {
        float mu = 0;
#pragma unroll
        for (int j = 0; j < 9; j++) mu += S.hst[w][lane * 9 + j];
        mu *= (1.f / 9.f);
        float var = 0;
#pragma unroll
        for (int j = 0; j < 9; j++) { float d0 = S.hst[w][lane * 9 + j] - mu; var = fmaf(d0, d0, var); }
        var *= (1.f / 9.f);
        float rs = rsqrtf(var + 1e-5f);
#pragma unroll
        for (int j = 0; j < 9; j++)
            S.hsn[w][lane * 9 + j] = (S.hst[w][lane * 9 + j] - mu) * rs * ldv(slg, j, f32) + ldv(slb, j, f32);
    }
    __syncthreads();   // SY3

    // ================= P3: structural projections =================
    if (bv) {
        int l = lane & 31;
        int m0 = (lane < 32) ? 0 : 5, m1 = (lane < 32) ? 5 : 9;
        for (int m = m0; m < m1; m++) {
            float a = 0;
#pragma unroll
            for (int j = 0; j < 9; j++) a = fmaf(S.hsn[w][m * 9 + j], g_tns[l * 9 + j], a);
            S.pb[w][m * 32 + l] = a;
        }
    }
    __syncthreads();   // SY4

    // ================= P4: structural sort -> Cs, t1s =================
    if (bv) {
        float t1 = 0;
        if (lane < 32) {
            float v[9]; int r[9];
#pragma unroll
            for (int m = 0; m < 9; m++) v[m] = S.pb[w][m * 32 + lane];
            rank9(v, r);
#pragma unroll
            for (int m = 0; m < 9; m++) {
                float wgt = (((mb >> (1 + m)) & 1) ? 1.f : 0.f) * inv;
                int slot = lane * 9 + r[m];
                S.Cs[w][slot]       = f2bf(wgt);
                S.Cs[w][288 + slot] = f2bf(-2.f * wgt * v[m]);
                t1 = fmaf(wgt * v[m], v[m], t1);
            }
        }
#pragma unroll
        for (int m = 16; m >= 1; m >>= 1) t1 += __shfl_xor(t1, m);
        if (lane == 0) S.sc[w][4] = t1;
    }
    __syncthreads();   // SY5

    // ================= P5: batched MFMA (wave = n-tile) + epilogue =================
    {
        f32x4 rd = {0.f, 0.f, 0.f, 0.f};
#pragma unroll
        for (int ks = 0; ks < 4; ks++) {
            short8 af = {0, 0, 0, 0, 0, 0, 0, 0};
            if (fm < NBM) af = *(const short8*)(S.h[fm] + ks * 32 + quad * 8);   // row 0 of b fm
            short8 bf = *(const short8*)(g_pBr + ((w * 4 + ks) * 64 + lane) * 8);
            rd = MFMA(af, bf, rd);
        }
        f32x4 accF = {0.f, 0.f, 0.f, 0.f}, accS = {0.f, 0.f, 0.f, 0.f};
#pragma unroll
        for (int ks = 0; ks < 18; ks++) {
            short8 aF = {0, 0, 0, 0, 0, 0, 0, 0}, aS = {0, 0, 0, 0, 0, 0, 0, 0};
            if (fm < NBM) {
                aF = *(const short8*)(S.Cf[fm] + ks * 32 + quad * 8);
                aS = *(const short8*)(S.Cs[fm] + ks * 32 + quad * 8);
            }
            short8 bF = *(const short8*)(g_pBx + ((w * 18 + ks) * 64 + lane) * 8);
            short8 bS = *(const short8*)(g_pBs + ((w * 18 + ks) * 64 + lane) * 8);
            accF = MFMA(aF, bF, accF);
            accS = MFMA(aS, bS, accS);
        }
        if (quad == 0) {
            int k = w * 16 + fm;
            float wl[NBM] = {0.f, 0.f, 0.f, 0.f};
#pragma unroll 4
            for (int j = 0; j < 32; j++) {
                float hptv = g_hpt[j * 64 + k];
                float w2v = ldv(wn_w2, j, f32);
#pragma unroll
                for (int reg = 0; reg < NBM; reg++)
                    wl[reg] = fmaf(fmaxf(S.hbv[reg][j] + hptv, 0.f), w2v, wl[reg]);
            }
            float wb2 = ldv(wn_b2, 0, f32);
            float wr  = ldv(w_raw, 0, f32);
            float gamma = expf(ldv(log_gamma, 0, f32));
            float hprnk = g_hprn[k];
#pragma unroll
            for (int reg = 0; reg < NBM; reg++) {
                int bb = blockIdx.x * NBM + reg;
                if (bb >= B) continue;
                float swf = (S.sc[reg][3] + accF[reg]) * (1.f / 32.f);
                float sws = (S.sc[reg][4] + accS[reg]) * (1.f / 32.f);
                float drfk = S.sc[reg][1] + hprnk - 2.f * rd[reg];
                float wgt = sigmoidf(wr + wl[reg] + wb2);
                float dfeat = wgt * drfk + (1.f - wgt) * swf;
                float dstr  = wgt * S.drad[reg][k] + (1.f - wgt) * sws;
                float al = S.sc[reg][2];
                float dfgw = al * dfeat + (1.f - al) * dstr;
                if (!(dfgw == dfgw)) dfgw = 1e30f;
                float res = expf(-gamma * dfgw);
                if (f32) ((float*)out)[bb * 64 + k] = res;
                else     ((u16*)out)[bb * 64 + k] = f2bf(res);
            }
        }
    }
}

extern "C" void kernel_launch(void* const* d_in, const int* in_sizes, int n_in,
                              void* d_out, int out_size, void* d_ws, size_t ws_size,
                              hipStream_t stream) {
    const void* adj  = d_in[0];
    const void* feat = d_in[1];
    const int*  idxs = (const int*)d_in[2];
    const void* xlw  = d_in[3];
    const void* xlb  = d_in[4];
    const void* xlg  = d_in[5];
    const void* xlbt = d_in[6];
    const void* slg  = d_in[7];
    const void* slb  = d_in[8];
    const void* thx  = d_in[9];
    const void* ths  = d_in[10];
    const void* araw = d_in[11];
    const void* anw1 = d_in[12];
    const void* anb1 = d_in[13];
    const void* anw2 = d_in[14];
    const void* anb2 = d_in[15];
    const void* wnw1 = d_in[16];
    const void* wnb1 = d_in[17];
    const void* wnw2 = d_in[18];
    const void* wnb2 = d_in[19];
    const void* wraw = d_in[20];
    const void* prt  = d_in[21];
    const void* prn  = d_in[22];
    const void* prad = d_in[23];
    const void* pdn  = d_in[24];
    const void* lgam = d_in[25];
    int B = in_sizes[2] / 10;

    k_proto<<<64, 256, 0, stream>>>(xlw, xlb, xlg, xlbt, slg, slb, wnw1,
                                    prt, prn, prad, pdn, thx, ths);
    k_main<<<(B + NBM - 1) / NBM, 256, 0, stream>>>(adj, idxs, feat,
                                  xlb, xlg, xlbt, slg, slb,
                                  anw1, anb1, anw2, anb2, wnw1, wnb1, wnw2, wnb2,
                                  araw, wraw, lgam, d_out, B);
}

// Round 11
// 278.505 us; speedup vs baseline: 1.0782x; 1.0782x over previous
//
#include <hip/hip_runtime.h>
#include <hip/hip_bf16.h>

typedef unsigned short u16;
typedef __attribute__((ext_vector_type(8))) short short8;   // 8 bf16 (4 VGPRs)
typedef __attribute__((ext_vector_type(4))) float f32x4;

#define NN 9
#define DX 128
#define KP 64
#define LL 32
#define NALL 100000
#define BMAX 8192
#define NBM 4
#define NBP 11

#define MFMA(a, b, c) __builtin_amdgcn_mfma_f32_16x16x32_bf16(a, b, c, 0, 0, 0)

// ---------- cross-kernel tables (written by k_linall, read by k_main) ----------
__device__ __align__(16) float g_tns[LL * NN];        // normalized theta_s [l][j]
__device__ __align__(16) float g_hprn[KP];            // ||h_proto_root||^2 [k]
__device__ __align__(16) float g_hpt[32 * KP];        // hp^T [j][k]
__device__ __align__(16) float g_rpst[NN * KP];       // sorted proto_rad [m][k]
__device__ __align__(16) u16   g_hx[BMAX * 10 * DX];  // batch LN'd h rows, bf16
// MFMA fragment-packed B tables (bf16)
__device__ __align__(16) u16   g_pBt[4096];           // tnx:  K=128, N=32
__device__ __align__(16) u16   g_pBr[8192];           // hprt: K=128, N=64
__device__ __align__(16) u16   g_pBx[36864];          // sw feat [pf^2|pf]: K=576, N=64
__device__ __align__(16) u16   g_pBs[36864];          // sw str  [qf^2|qf]: K=576, N=64

__device__ __forceinline__ float bf2f(u16 u) {
    union { unsigned u; float f; } v; v.u = ((unsigned)u) << 16; return v.f;
}
__device__ __forceinline__ u16 f2bf(float f) {
    __hip_bfloat16 h = __float2bfloat16(f);
    union { __hip_bfloat16 h; u16 u; } v; v.h = h; return v.u;
}
__device__ __forceinline__ float ldv(const void* p, long i, int f32) {
    return f32 ? ((const float*)p)[i] : bf2f(((const u16*)p)[i]);
}
__device__ __forceinline__ float sigmoidf(float x) { return 1.f / (1.f + expf(-x)); }

__device__ __forceinline__ int bfrag_idx(int ksteps, int ncol, int kd) {
    int ntile = ncol >> 4, n = ncol & 15;
    int kstep = kd >> 5, quad = (kd >> 3) & 3, j = kd & 7;
    return ((ntile * ksteps + kstep) * 64 + quad * 16 + n) * 8 + j;
}

__device__ __forceinline__ void rank9(const float* v, int* r) {
#pragma unroll
    for (int m = 0; m < 9; m++) {
        int rk = 0;
#pragma unroll
        for (int n = 0; n < 9; n++)
            rk += (v[n] < v[m]) || (v[n] == v[m] && n < m);
        r[m] = rk;
    }
}

// ---------------- kernel 1: lin+LN for ALL rows; proto blocks run full proto chain ----------------
// blockIdx < NBP: proto blocks (60 proto rows = 6 k's), chain fused, hidden under batch blocks.
// blockIdx >= NBP: batch blocks (60 gathered rows -> g_hx bf16).
__global__ __launch_bounds__(256) void k_linall(
    const void* feat, const int* idxs,
    const void* proto_root, const void* proto_neigh,
    const void* xlw, const void* xlb, const void* xlg, const void* xlbt,
    const void* slg, const void* slb, const void* wn_w1,
    const void* proto_rad, const void* proto_dn,
    const void* theta_x, const void* theta_s, int B) {
    // LDS: [0,32768) phase A = Wf (W frags); phase B (proto) = pBtL/tnsL/pbX/Cm/hsnP
    //      [32768,48128) hXpb: proto LN'd h rows bf16 (60 rows x 128)
    __shared__ __align__(16) unsigned char sm[48128];
    u16*   Wf   = (u16*)sm;
    u16*   pBtL = (u16*)sm;                   // phase B alias
    float* tnsL = (float*)(sm + 8192);
    float* pbX  = (float*)(sm + 9344);        // [6][288] f32 (also reused for pbS)
    float* Cm   = (float*)(sm + 16256);       // [6][81]
    float* hsnP = (float*)(sm + 18200);       // [6][81]
    u16*   hXpb = (u16*)(sm + 32768);         // [60][128] bf16

    int t = threadIdx.x, lane = t & 63, w = t >> 6;
    const int f32 = (((const u16*)xlg)[0] == 0);
    int fm = lane & 15, quad = lane >> 4;
    bool isProto = (blockIdx.x < (unsigned)NBP);
    int base = isProto ? blockIdx.x * 60 : (blockIdx.x - NBP) * 60;
    int rowT = isProto ? KP * 10 : B * 10;

    // ---- pack W into LDS B-fragment layout ----
    for (int i = t; i < 16384; i += 256) {
        int c = i >> 7, d = i & 127;
        Wf[bfrag_idx(4, d, c)] = f2bf(ldv(xlw, i, f32));
    }

    float bias[8], gg[8], bb[8];
#pragma unroll
    for (int nt = 0; nt < 8; nt++) {
        int col = nt * 16 + fm;
        bias[nt] = ldv(xlb, col, f32);
        gg[nt]   = ldv(xlg, col, f32);
        bb[nt]   = ldv(xlbt, col, f32);
    }

    int lr = w * 16 + fm, gr = base + lr;
    bool azero = true;
    const void* abuf = feat; long aoff = 0;
    if (lr < 60 && gr < rowT) {
        if (!isProto) {
            int id = idxs[gr];
            if (id != NALL) { azero = false; aoff = (long)id * 128; }
        } else {
            int rr = gr % 10; azero = false;
            if (rr < 9) { abuf = proto_neigh; aoff = (long)((gr / 10) * 9 + rr) * 128; }
            else        { abuf = proto_root;  aoff = (long)(gr / 10) * 128; }
        }
    }
    __syncthreads();

    f32x4 acc[8];
#pragma unroll
    for (int nt = 0; nt < 8; nt++) acc[nt] = (f32x4){0.f, 0.f, 0.f, 0.f};
#pragma unroll
    for (int ks = 0; ks < 4; ks++) {
        short8 af = {0, 0, 0, 0, 0, 0, 0, 0};
        if (!azero) {
            if (f32) {
                const f32x4* src = (const f32x4*)((const float*)abuf + aoff + ks * 32 + quad * 8);
                f32x4 v0 = src[0], v1 = src[1];
                u16* ap = (u16*)&af;
#pragma unroll
                for (int j = 0; j < 4; j++) { ap[j] = f2bf(v0[j]); ap[4 + j] = f2bf(v1[j]); }
            } else {
                af = *(const short8*)((const u16*)abuf + aoff + ks * 32 + quad * 8);
            }
        }
#pragma unroll
        for (int nt = 0; nt < 8; nt++) {
            short8 bf = *(const short8*)(Wf + ((nt * 4 + ks) * 64 + lane) * 8);
            acc[nt] = MFMA(af, bf, acc[nt]);
        }
    }
#pragma unroll
    for (int nt = 0; nt < 8; nt++)
#pragma unroll
        for (int reg = 0; reg < 4; reg++) acc[nt][reg] += bias[nt];

#pragma unroll
    for (int reg = 0; reg < 4; reg++) {
        float s = 0, q = 0;
#pragma unroll
        for (int nt = 0; nt < 8; nt++) {
            s += acc[nt][reg];
            q = fmaf(acc[nt][reg], acc[nt][reg], q);
        }
#pragma unroll
        for (int m = 1; m < 16; m <<= 1) { s += __shfl_xor(s, m); q += __shfl_xor(q, m); }
        float mu = s * (1.f / 128.f);
        float var = fmaxf(q * (1.f / 128.f) - mu * mu, 0.f);
        float rs = rsqrtf(var + 1e-5f);
        int rowD = w * 16 + quad * 4 + reg, grD = base + rowD;
        if (rowD < 60 && grD < rowT) {
#pragma unroll
            for (int nt = 0; nt < 8; nt++) {
                float val = (acc[nt][reg] - mu) * rs * gg[nt] + bb[nt];
                if (!isProto) g_hx[grD * 128 + nt * 16 + fm] = f2bf(val);
                else          hXpb[rowD * 128 + nt * 16 + fm] = f2bf(val);
            }
        }
    }
    if (!isProto) return;

    // ================= proto chain (block-uniform path) =================
    __syncthreads();   // hXpb ready; Wf dead
    int kbase = blockIdx.x * 6;
    int kcnt = KP - kbase; if (kcnt > 6) kcnt = 6;

    // theta pack (aliases Wf region — safe after barrier)
    if (t < 32) {
        float s = 0;
        for (int d = 0; d < 128; d++) { float v = ldv(theta_x, t * 128 + d, f32); s = fmaf(v, v, s); }
        float inv = 1.f / sqrtf(s);
        for (int d = 0; d < 128; d++)
            pBtL[bfrag_idx(4, t, d)] = f2bf(ldv(theta_x, t * 128 + d, f32) * inv);
    } else if (t < 64) {
        int l = t - 32;
        float s = 0;
        for (int j = 0; j < 9; j++) { float v = ldv(theta_s, l * 9 + j, f32); s = fmaf(v, v, s); }
        float inv = 1.f / sqrtf(s);
        for (int j = 0; j < 9; j++) tnsL[l * 9 + j] = ldv(theta_s, l * 9 + j, f32) * inv;
    }
    __syncthreads();

    if (blockIdx.x == 0) {   // publish packed theta tables for k_main
        for (int i = t; i < 4096; i += 256) g_pBt[i] = pBtL[i];
        for (int i = t; i < 288; i += 256) g_tns[i] = tnsL[i];
    }
    // pBr copy (already bf16), hprn, hpt, rpst
    for (int i = t; i < kcnt * 128; i += 256) {
        int kl = i >> 7, d = i & 127;
        g_pBr[bfrag_idx(4, kbase + kl, d)] = hXpb[kl * 1280 + 1152 + d];
    }
    for (int kl = w; kl < kcnt; kl += 4) {
        float v0 = bf2f(hXpb[kl * 1280 + 1152 + lane]);
        float v1 = bf2f(hXpb[kl * 1280 + 1216 + lane]);
        float q = v0 * v0 + v1 * v1;
#pragma unroll
        for (int m = 32; m >= 1; m >>= 1) q += __shfl_xor(q, m);
        if (lane == 0) g_hprn[kbase + kl] = q;
    }
    for (int i = t; i < kcnt * 32; i += 256) {
        int kl = i >> 5, j = i & 31;
        float acc2 = 0;
        for (int d = 0; d < 128; d++)
            acc2 = fmaf(bf2f(hXpb[kl * 1280 + 1152 + d]), ldv(wn_w1, (128 + d) * 32 + j, f32), acc2);
        g_hpt[j * 64 + kbase + kl] = acc2;
    }
    if (t < kcnt) {
        float v[9]; int r[9];
#pragma unroll
        for (int m = 0; m < 9; m++) v[m] = ldv(proto_rad, (kbase + t) * 9 + m, f32);
        rank9(v, r);
#pragma unroll
        for (int m = 0; m < 9; m++) g_rpst[r[m] * 64 + kbase + t] = v[m];
    }
    // feature projections MFMA per k (wave = k)
    for (int kl = w; kl < kcnt; kl += 4) {
        f32x4 acc0 = {0.f, 0.f, 0.f, 0.f}, acc1 = {0.f, 0.f, 0.f, 0.f};
        const u16* arow = hXpb + kl * 1280 + fm * 128;
#pragma unroll
        for (int ks = 0; ks < 4; ks++) {
            short8 af = {0, 0, 0, 0, 0, 0, 0, 0};
            if (fm < 9) af = *(const short8*)(arow + ks * 32 + quad * 8);
            short8 b0 = *(const short8*)(pBtL + ((0 * 4 + ks) * 64 + lane) * 8);
            short8 b1 = *(const short8*)(pBtL + ((1 * 4 + ks) * 64 + lane) * 8);
            acc0 = MFMA(af, b0, acc0);
            acc1 = MFMA(af, b1, acc1);
        }
#pragma unroll
        for (int reg = 0; reg < 4; reg++) {
            int row = quad * 4 + reg;
            if (row < 9) {
                pbX[kl * 288 + row * 32 + fm]      = acc0[reg];
                pbX[kl * 288 + row * 32 + 16 + fm] = acc1[reg];
            }
        }
    }
    // C build
    for (int i = t; i < kcnt * 81; i += 256) {
        int kl = i / 81, ij = i - kl * 81;
        int ii = ij / 9, jj = ij % 9; float v = 0.f;
        if (ii != jj) {
            int a = (ii < jj) ? ii : jj, b2 = (ii < jj) ? jj : ii;
            int p = a * 8 - a * (a - 1) / 2 + (b2 - a - 1);
            v = sigmoidf(ldv(proto_dn, p * 64 + kbase + kl, f32));
        }
        Cm[kl * 81 + ij] = v;
    }
    __syncthreads();
    // sort pbX -> g_pBx
    for (int i = t; i < kcnt * 32; i += 256) {
        int kl = i >> 5, l = i & 31;
        float v[9]; int r[9];
#pragma unroll
        for (int m = 0; m < 9; m++) v[m] = pbX[kl * 288 + m * 32 + l];
        rank9(v, r);
#pragma unroll
        for (int m = 0; m < 9; m++) {
            int kd = l * 9 + r[m];
            g_pBx[bfrag_idx(18, kbase + kl, kd)]       = f2bf(v[m] * v[m]);
            g_pBx[bfrag_idx(18, kbase + kl, 288 + kd)] = f2bf(v[m]);
        }
    }
    // col sort Cm
    for (int i = t; i < kcnt * 9; i += 256) {
        int kl = i / 9, col = i - kl * 9;
        float v[9]; int r[9];
#pragma unroll
        for (int j = 0; j < 9; j++) v[j] = Cm[kl * 81 + j * 9 + col];
        rank9(v, r);
#pragma unroll
        for (int j = 0; j < 9; j++) Cm[kl * 81 + r[j] * 9 + col] = v[j];
    }
    __syncthreads();
    // LN rows of sorted Cm -> hsnP
    for (int i = t; i < kcnt * 9; i += 256) {
        int kl = i / 9, row = i - kl * 9;
        float mu = 0;
#pragma unroll
        for (int j = 0; j < 9; j++) mu += Cm[kl * 81 + row * 9 + j];
        mu *= (1.f / 9.f);
        float var = 0;
#pragma unroll
        for (int j = 0; j < 9; j++) { float d0 = Cm[kl * 81 + row * 9 + j] - mu; var = fmaf(d0, d0, var); }
        var *= (1.f / 9.f);
        float rs = rsqrtf(var + 1e-5f);
#pragma unroll
        for (int j = 0; j < 9; j++)
            hsnP[kl * 81 + row * 9 + j] = (Cm[kl * 81 + row * 9 + j] - mu) * rs * ldv(slg, j, f32) + ldv(slb, j, f32);
    }
    __syncthreads();
    // structural projections (reuse pbX region)
    for (int i = t; i < kcnt * 32; i += 256) {
        int kl = i >> 5, l = i & 31;
#pragma unroll
        for (int m = 0; m < 9; m++) {
            float a = 0;
#pragma unroll
            for (int j = 0; j < 9; j++) a = fmaf(hsnP[kl * 81 + m * 9 + j], tnsL[l * 9 + j], a);
            pbX[kl * 288 + m * 32 + l] = a;
        }
    }
    __syncthreads();
    // sort pbS -> g_pBs
    for (int i = t; i < kcnt * 32; i += 256) {
        int kl = i >> 5, l = i & 31;
        float v[9]; int r[9];
#pragma unroll
        for (int m = 0; m < 9; m++) v[m] = pbX[kl * 288 + m * 32 + l];
        rank9(v, r);
#pragma unroll
        for (int m = 0; m < 9; m++) {
            int kd = l * 9 + r[m];
            g_pBs[bfrag_idx(18, kbase + kl, kd)]       = f2bf(v[m] * v[m]);
            g_pBs[bfrag_idx(18, kbase + kl, 288 + kd)] = f2bf(v[m]);
        }
    }
}

// ---------------- kernel 2: 4 b's per block, one wave per b (R9 version) ----------------
struct M3 {
    u16   Cf[NBM][576];     // [wgt | -2*wgt*v]
    u16   Cs[NBM][576];
    u16   hroot[NBM][128];
    float pb[NBM][288];
    float df[NBM][100];
    float hst[NBM][81], hsn[NBM][81];
    float drad[NBM][64];
    float hbv[NBM][32];
    float hpool[NBM][128];
    float rbss[NBM][9], wrad[NBM][9];
    float sc[NBM][8];       // 1:hrn 2:alpha 3:t1x 4:t1s
};
__global__ __launch_bounds__(256) void k_main(
    const void* adj, const int* idxs,
    const void* slg, const void* slb,
    const void* an_w1, const void* an_b1, const void* an_w2, const void* an_b2,
    const void* wn_w1, const void* wn_b1, const void* wn_w2, const void* wn_b2,
    const void* alpha_raw, const void* w_raw, const void* log_gamma,
    const void* xlg, void* out, int B) {
    __shared__ __align__(16) M3 S;
    int t = threadIdx.x, lane = t & 63, w = t >> 6;
    const int f32 = (((const u16*)xlg)[0] == 0);
    int fm = lane & 15, quad = lane >> 4;
    int bw = blockIdx.x * NBM + w;
    bool bv = (bw < B);

    unsigned long long mb = 0; float nv = 1e-9f, inv = 0.f;

    // ================= P0 =================
    if (bv) {
        bool valid = false;
        if (lane < 10) {
            int id = idxs[bw * 10 + lane];
            valid = (lane == 0) || (id != NALL);
        }
        mb = __ballot(valid);
        nv = (float)__popcll(mb & 0x3FEull) + 1e-9f;
        inv = 1.f / nv;
        unsigned rowbits = 0;
        if (lane < 10) {
            for (int j = 0; j < 10; j++)
                if (ldv(adj, (long)bw * 100 + lane * 10 + j, f32) > 1e-5f) rowbits |= 1u << j;
        }
        int dl[10];
#pragma unroll
        for (int j = 0; j < 10; j++) dl[j] = (j == lane) ? 0 : (((rowbits >> j) & 1) ? 1 : 10);
        unsigned reach = (lane < 10) ? (rowbits | (1u << lane)) : 0u;
        for (int s = 2; s <= 9; s++) {
            unsigned nr = reach;
#pragma unroll
            for (int j = 0; j < 10; j++) {
                unsigned rj = __shfl(rowbits, j);
                if ((reach >> j) & 1) nr |= rj;
            }
            unsigned add = nr & ~reach;
#pragma unroll
            for (int j = 0; j < 10; j++) if ((add >> j) & 1) dl[j] = s;
            reach = nr;
            if (__all(add == 0)) break;
        }
        if (lane < 10) {
            int mi = (int)((mb >> lane) & 1);
#pragma unroll
            for (int j = 0; j < 10; j++) {
                int mj = (int)((mb >> j) & 1);
                S.df[w][lane * 10 + j] = (mi && mj) ? (float)dl[j] * 0.1f : 1.0f;
            }
            if (lane == 0) {
                float v[9]; int r[9];
#pragma unroll
                for (int m = 0; m < 9; m++)
                    v[m] = ((mb >> (1 + m)) & 1) ? (float)dl[1 + m] * 0.1f : 1.0f;
                rank9(v, r);
#pragma unroll
                for (int m = 0; m < 9; m++) {
                    S.rbss[w][r[m]] = v[m];
                    S.wrad[w][r[m]] = (((mb >> (1 + m)) & 1) ? 1.f : 0.f) * inv;
                }
            }
        }
        {
            u16 u0 = g_hx[bw * 1280 + lane], u1 = g_hx[bw * 1280 + 64 + lane];
            S.hroot[w][lane] = u0; S.hroot[w][64 + lane] = u1;
            float v0 = bf2f(u0), v1 = bf2f(u1);
            float q = v0 * v0 + v1 * v1;
#pragma unroll
            for (int m = 32; m >= 1; m >>= 1) q += __shfl_xor(q, m);
            if (lane == 0) S.sc[w][1] = q;
        }
        for (int dd = lane; dd < 128; dd += 64) {
            float a = 0;
#pragma unroll
            for (int m = 0; m < 9; m++) {
                float hv = bf2f(g_hx[bw * 1280 + (1 + m) * 128 + dd]);
                float msk = ((mb >> (1 + m)) & 1) ? 1.f : 0.f;
                a = fmaf(hv, msk, a);
            }
            S.hpool[w][dd] = a * inv;
        }
        {
            f32x4 acc0 = {0.f, 0.f, 0.f, 0.f}, acc1 = {0.f, 0.f, 0.f, 0.f};
            const u16* arow = g_hx + (bw * 10 + 1 + fm) * 128;
#pragma unroll
            for (int ks = 0; ks < 4; ks++) {
                short8 af = {0, 0, 0, 0, 0, 0, 0, 0};
                if (fm < 9) af = *(const short8*)(arow + ks * 32 + quad * 8);
                short8 b0 = *(const short8*)(g_pBt + ((0 * 4 + ks) * 64 + lane) * 8);
                short8 b1 = *(const short8*)(g_pBt + ((1 * 4 + ks) * 64 + lane) * 8);
                acc0 = MFMA(af, b0, acc0);
                acc1 = MFMA(af, b1, acc1);
            }
#pragma unroll
            for (int reg = 0; reg < 4; reg++) {
                int row = quad * 4 + reg;
                if (row < 9) {
                    S.pb[w][row * 32 + fm]      = acc0[reg];
                    S.pb[w][row * 32 + 16 + fm] = acc1[reg];
                }
            }
        }
    }
    __syncthreads();   // SY1

    // ================= P1 =================
    if (bv) {
        float t1 = 0;
        if (lane < 32) {
            float v[9]; int r[9];
#pragma unroll
            for (int m = 0; m < 9; m++) v[m] = S.pb[w][m * 32 + lane];
            rank9(v, r);
#pragma unroll
            for (int m = 0; m < 9; m++) {
                float wgt = (((mb >> (1 + m)) & 1) ? 1.f : 0.f) * inv;
                int slot = lane * 9 + r[m];
                S.Cf[w][slot]       = f2bf(wgt);
                S.Cf[w][288 + slot] = f2bf(-2.f * wgt * v[m]);
                t1 = fmaf(wgt * v[m], v[m], t1);
            }
        }
#pragma unroll
        for (int m = 16; m >= 1; m >>= 1) t1 += __shfl_xor(t1, m);
        if (lane == 0) S.sc[w][3] = t1;
        if (lane < 9) {
            float v[9]; int r[9];
#pragma unroll
            for (int i = 0; i < 9; i++) v[i] = S.df[w][(1 + i) * 10 + 1 + lane];
            rank9(v, r);
#pragma unroll
            for (int i = 0; i < 9; i++) S.hst[w][r[i] * 9 + lane] = v[i];
        }
        {
            float acc = 0;
#pragma unroll
            for (int m = 0; m < 9; m++) {
                float d0 = S.rbss[w][m] - g_rpst[m * 64 + lane];
                acc = fmaf(d0 * d0, S.wrad[w][m], acc);
            }
            S.drad[w][lane] = acc;
        }
        {
            int j = lane & 31, half = lane >> 5;
            float acc = 0;
            for (int d = half * 64; d < half * 64 + 64; d++)
                acc = fmaf(S.hpool[w][d], ldv(an_w1, d * 32 + j, f32), acc);
            acc += __shfl_xor(acc, 32);
            float red = 0;
            if (lane < 32)
                red = fmaxf(acc + ldv(an_b1, j, f32), 0.f) * ldv(an_w2, j, f32);
#pragma unroll
            for (int m = 16; m >= 1; m >>= 1) red += __shfl_xor(red, m);
            if (lane == 0)
                S.sc[w][2] = sigmoidf(ldv(alpha_raw, 0, f32) + red + ldv(an_b2, 0, f32));
        }
        {
            int j = lane & 31, half = lane >> 5;
            float acc = 0;
            for (int d = half * 64; d < half * 64 + 64; d++)
                acc = fmaf(bf2f(g_hx[bw * 1280 + d]), ldv(wn_w1, d * 32 + j, f32), acc);
            acc += __shfl_xor(acc, 32);
            if (lane < 32) S.hbv[w][j] = acc + ldv(wn_b1, j, f32);
        }
    }
    __syncthreads();   // SY2

    // ================= P2 =================
    if (bv && lane < 9) {
        float mu = 0;
#pragma unroll
        for (int j = 0; j < 9; j++) mu += S.hst[w][lane * 9 + j];
        mu *= (1.f / 9.f);
        float var = 0;
#pragma unroll
        for (int j = 0; j < 9; j++) { float d0 = S.hst[w][lane * 9 + j] - mu; var = fmaf(d0, d0, var); }
        var *= (1.f / 9.f);
        float rs = rsqrtf(var + 1e-5f);
#pragma unroll
        for (int j = 0; j < 9; j++)
            S.hsn[w][lane * 9 + j] = (S.hst[w][lane * 9 + j] - mu) * rs * ldv(slg, j, f32) + ldv(slb, j, f32);
    }
    __syncthreads();   // SY3

    // ================= P3 =================
    if (bv) {
        int l = lane & 31;
        int m0 = (lane < 32) ? 0 : 5, m1 = (lane < 32) ? 5 : 9;
        for (int m = m0; m < m1; m++) {
            float a = 0;
#pragma unroll
            for (int j = 0; j < 9; j++) a = fmaf(S.hsn[w][m * 9 + j], g_tns[l * 9 + j], a);
            S.pb[w][m * 32 + l] = a;
        }
    }
    __syncthreads();   // SY4

    // ================= P4 =================
    if (bv) {
        float t1 = 0;
        if (lane < 32) {
            float v[9]; int r[9];
#pragma unroll
            for (int m = 0; m < 9; m++) v[m] = S.pb[w][m * 32 + lane];
            rank9(v, r);
#pragma unroll
            for (int m = 0; m < 9; m++) {
                float wgt = (((mb >> (1 + m)) & 1) ? 1.f : 0.f) * inv;
                int slot = lane * 9 + r[m];
                S.Cs[w][slot]       = f2bf(wgt);
                S.Cs[w][288 + slot] = f2bf(-2.f * wgt * v[m]);
                t1 = fmaf(wgt * v[m], v[m], t1);
            }
        }
#pragma unroll
        for (int m = 16; m >= 1; m >>= 1) t1 += __shfl_xor(t1, m);
        if (lane == 0) S.sc[w][4] = t1;
    }
    __syncthreads();   // SY5

    // ================= P5: batched MFMA + epilogue =================
    {
        f32x4 rd = {0.f, 0.f, 0.f, 0.f};
#pragma unroll
        for (int ks = 0; ks < 4; ks++) {
            short8 af = {0, 0, 0, 0, 0, 0, 0, 0};
            if (fm < NBM) af = *(const short8*)(S.hroot[fm] + ks * 32 + quad * 8);
            short8 bf = *(const short8*)(g_pBr + ((w * 4 + ks) * 64 + lane) * 8);
            rd = MFMA(af, bf, rd);
        }
        f32x4 accF = {0.f, 0.f, 0.f, 0.f}, accS = {0.f, 0.f, 0.f, 0.f};
#pragma unroll
        for (int ks = 0; ks < 18; ks++) {
            short8 aF = {0, 0, 0, 0, 0, 0, 0, 0}, aS = {0, 0, 0, 0, 0, 0, 0, 0};
            if (fm < NBM) {
                aF = *(const short8*)(S.Cf[fm] + ks * 32 + quad * 8);
                aS = *(const short8*)(S.Cs[fm] + ks * 32 + quad * 8);
            }
            short8 bF = *(const short8*)(g_pBx + ((w * 18 + ks) * 64 + lane) * 8);
            short8 bS = *(const short8*)(g_pBs + ((w * 18 + ks) * 64 + lane) * 8);
            accF = MFMA(aF, bF, accF);
            accS = MFMA(aS, bS, accS);
        }
        if (quad == 0) {
            int k = w * 16 + fm;
            float wl[NBM] = {0.f, 0.f, 0.f, 0.f};
#pragma unroll 4
            for (int j = 0; j < 32; j++) {
                float hptv = g_hpt[j * 64 + k];
                float w2v = ldv(wn_w2, j, f32);
#pragma unroll
                for (int reg = 0; reg < NBM; reg++)
                    wl[reg] = fmaf(fmaxf(S.hbv[reg][j] + hptv, 0.f), w2v, wl[reg]);
            }
            float wb2 = ldv(wn_b2, 0, f32);
            float wr  = ldv(w_raw, 0, f32);
            float gamma = expf(ldv(log_gamma, 0, f32));
            float hprnk = g_hprn[k];
#pragma unroll
            for (int reg = 0; reg < NBM; reg++) {
                int bb = blockIdx.x * NBM + reg;
                if (bb >= B) continue;
                float swf = (S.sc[reg][3] + accF[reg]) * (1.f / 32.f);
                float sws = (S.sc[reg][4] + accS[reg]) * (1.f / 32.f);
                float drfk = S.sc[reg][1] + hprnk - 2.f * rd[reg];
                float wgt = sigmoidf(wr + wl[reg] + wb2);
                float dfeat = wgt * drfk + (1.f - wgt) * swf;
                float dstr  = wgt * S.drad[reg][k] + (1.f - wgt) * sws;
                float al = S.sc[reg][2];
                float dfgw = al * dfeat + (1.f - al) * dstr;
                if (!(dfgw == dfgw)) dfgw = 1e30f;
                float res = expf(-gamma * dfgw);
                if (f32) ((float*)out)[bb * 64 + k] = res;
                else     ((u16*)out)[bb * 64 + k] = f2bf(res);
            }
        }
    }
}

extern "C" void kernel_launch(void* const* d_in, const int* in_sizes, int n_in,
                              void* d_out, int out_size, void* d_ws, size_t ws_size,
                              hipStream_t stream) {
    const void* adj  = d_in[0];
    const void* feat = d_in[1];
    const int*  idxs = (const int*)d_in[2];
    const void* xlw  = d_in[3];
    const void* xlb  = d_in[4];
    const void* xlg  = d_in[5];
    const void* xlbt = d_in[6];
    const void* slg  = d_in[7];
    const void* slb  = d_in[8];
    const void* thx  = d_in[9];
    const void* ths  = d_in[10];
    const void* araw = d_in[11];
    const void* anw1 = d_in[12];
    const void* anb1 = d_in[13];
    const void* anw2 = d_in[14];
    const void* anb2 = d_in[15];
    const void* wnw1 = d_in[16];
    const void* wnb1 = d_in[17];
    const void* wnw2 = d_in[18];
    const void* wnb2 = d_in[19];
    const void* wraw = d_in[20];
    const void* prt  = d_in[21];
    const void* prn  = d_in[22];
    const void* prad = d_in[23];
    const void* pdn  = d_in[24];
    const void* lgam = d_in[25];
    int B = in_sizes[2] / 10;
    int NBQ = (B * 10 + 59) / 60;

    k_linall<<<NBP + NBQ, 256, 0, stream>>>(feat, idxs, prt, prn,
                                            xlw, xlb, xlg, xlbt, slg, slb, wnw1,
                                            prad, pdn, thx, ths, B);
    k_main<<<(B + NBM - 1) / NBM, 256, 0, stream>>>(adj, idxs, slg, slb,
                                  anw1, anb1, anw2, anb2, wnw1, wnb1, wnw2, wnb2,
                                  araw, wraw, lgam, xlg, d_out, B);
}